// Round 16
// baseline (131.176 us; speedup 1.0000x reference)
//
#include <hip/hip_runtime.h>

#define MM 4096
#define NN 4096
#define KK 4096
#define BM 256
#define BN 256
#define BK 64
#define NT (KK / BK)

typedef short          s16x8 __attribute__((ext_vector_type(8)));
typedef float          f32x4 __attribute__((ext_vector_type(4)));
typedef unsigned short us4   __attribute__((ext_vector_type(4)));
typedef unsigned short us8   __attribute__((ext_vector_type(8)));

#define MFMA16(a, b, c) __builtin_amdgcn_mfma_f32_16x16x32_bf16((a), (b), (c), 0, 0, 0)
#define SB0() __builtin_amdgcn_sched_barrier(0)
#define LGKM(n) asm volatile("s_waitcnt lgkmcnt(" #n ")" ::: "memory")
#define VMC(n)  asm volatile("s_waitcnt vmcnt(" #n ")" ::: "memory")

// ---------- helpers ----------

__device__ __forceinline__ unsigned short f2bf(float f) {
  unsigned int u = __float_as_uint(f);
  u += 0x7fffu + ((u >> 16) & 1u);
  return (unsigned short)(u >> 16);
}

__device__ __forceinline__ void gload16(const void* g, void* l) {
  __builtin_amdgcn_global_load_lds(
      (const __attribute__((address_space(1))) void*)g,
      (__attribute__((address_space(3))) void*)l, 16, 0, 0);
}

// ---------- kernel 1: fused preprocessing ----------
// blocks [0, 8192):  2:4 mask + binarize + cvt -> W_h bf16 (M x K)
// blocks [8192, 12288): x (K x N f32) -> xT (N x K bf16).
//   Transpose tile = 128k x 32n with [k][n] LDS layout so the store phase
//   emits 16B us8 per lane, 256B contiguous per 16-lane group (vs 8B in the
//   old 64x64 variant).

__global__ __launch_bounds__(256) void kpre(const float* __restrict__ w,
                                            const float* __restrict__ x,
                                            unsigned short* __restrict__ wh,
                                            unsigned short* __restrict__ xt) {
  __shared__ float tile[128][33];
  const int t = threadIdx.x;

  if (blockIdx.x < 8192) {
    // ---- quant path ----
    int idx = blockIdx.x * 256 + t;
    const float4* p = (const float4*)w;
    float4 g0 = p[(size_t)idx * 2];
    float4 g1 = p[(size_t)idx * 2 + 1];
    float v[8] = {g0.x, g0.y, g0.z, g0.w, g1.x, g1.y, g1.z, g1.w};
    us8 o;
#pragma unroll
    for (int g = 0; g < 2; g++) {
      float av[4];
#pragma unroll
      for (int j = 0; j < 4; j++) av[j] = fabsf(v[g * 4 + j]);
#pragma unroll
      for (int j = 0; j < 4; j++) {
        int rank = 0;
#pragma unroll
        for (int k = 0; k < 4; k++) {
          if (k == j) continue;
          rank += (av[k] > av[j] || (av[k] == av[j] && k < j)) ? 1 : 0;
        }
        o[g * 4 + j] = (rank < 2 && v[g * 4 + j] > 0.0f) ? (unsigned short)0x3F80
                                                         : (unsigned short)0;
      }
    }
    *(us8*)(wh + (size_t)idx * 8) = o;
    return;
  }

  // ---- transpose path: tile 128k x 32n ----
  int bid2 = blockIdx.x - 8192;              // 0..4095
  int bn = bid2 & 127;                       // n-tile (4096/32)
  int bk = bid2 >> 7;                        // k-tile (4096/128)
  // load: thread covers 4 n-cols x 4 k-rows
  const int nc = (t & 7) << 2;               // 0..28
  const int kr = t >> 3;                     // 0..31
  const float* src = x + (size_t)(bk * 128 + kr) * NN + bn * 32 + nc;
#pragma unroll
  for (int p = 0; p < 4; p++) {
    float4 v = *(const float4*)(src + (size_t)p * 32 * NN);
    int k = kr + p * 32;
    tile[k][nc + 0] = v.x; tile[k][nc + 1] = v.y;
    tile[k][nc + 2] = v.z; tile[k][nc + 3] = v.w;
  }
  __syncthreads();
  // store: 16 lanes span 128 k (8 each, us8=16B) -> 256B contiguous segments
  const int kc = (t & 15) << 3;              // 0..120
  const int nr = t >> 4;                     // 0..15
#pragma unroll
  for (int p = 0; p < 2; p++) {
    int n = nr + p * 16;
    us8 o;
#pragma unroll
    for (int j = 0; j < 8; j++) o[j] = f2bf(tile[kc + j][n]);
    *(us8*)(xt + (size_t)(bn * 32 + n) * KK + bk * 128 + kc) = o;
  }
}

// ---------- kernel 2: 256x256 GEMM, balanced 12/12 read split -------------
// (r15 champion; change: readAF2/readB1 hoisted ABOVE the stage block so the
// LDS pipe starts earlier — DS/VMEM counters are independent, ledger intact.)
// Per-wave ledger (in-order DS retire):
//   top: out=12 {lo of t}; +12 {af2;b1 of t} -> out=24
//   LGKM(12) => lo ready -> Q00 ; LGKM(4) => af2 ready -> Q10
//   VMC(0)+barrier (buf^1 certified)
//   +4 {b0 of t+1} ; LGKM(4) => b1 ready -> Q01
//   +8 {af of t+1} ; Q11 ; loop (invariant restored)

__global__ __launch_bounds__(512, 2) void kgemm(const unsigned short* __restrict__ A,
                                                const unsigned short* __restrict__ B,
                                                float* __restrict__ C) {
  __shared__ __align__(16) unsigned short lds[4 * BM * BK];  // A0|A1|B0|B1, 128 KiB

  const int tid  = threadIdx.x;
  // XCD swizzle: xcd = bid&7; each XCD owns a 4x8 rectangle of the 16x16 grid.
  const int bid  = blockIdx.x;
  const int xcd  = bid & 7;
  const int j    = bid >> 3;
  const int bmi  = (xcd >> 1) * 4 + (j >> 3);
  const int bni  = (xcd & 1) * 8 + (j & 7);
  const int lane = tid & 63;
  const int wave = tid >> 6;
  const int wm   = wave >> 2;
  const int wn   = wave & 3;
  const int llo  = lane & 15;
  const int lhi  = lane >> 4;

  // staging addresses (linear LDS dest; inverse-swizzled global source)
  const int srow  = tid >> 3;
  const int scol  = (tid & 7) << 3;
  const int scolz = scol ^ ((srow & 7) << 3);
  const unsigned short* ga = A + (size_t)(bmi * BM + srow) * KK + scolz;
  const unsigned short* gb = B + (size_t)(bni * BN + srow) * KK + scolz;

  // fragment read offsets (swizzled) — proven 0-conflict pattern
  const int swz  = (llo & 7) << 3;
  const int ok0  = (lhi * 8) ^ swz;
  const int ok1  = (32 + lhi * 8) ^ swz;
  const int arow = (wm * 128 + llo) * BK;
  const int brow = (wn * 64 + llo) * BK;

  f32x4 acc[8][4] = {};
  s16x8 af[4][2], af2[4][2], b0[2][2], b1[2][2];

  auto stageA = [&](int buf, int t, int h) {
    const unsigned short* p = ga + (size_t)t * BK;
    unsigned short* l = &lds[buf * 16384 + tid * 8];
#pragma unroll
    for (int jj = 0; jj < 2; jj++)
      gload16(p + (size_t)(2 * h + jj) * 64 * KK, l + (2 * h + jj) * 4096);
  };
  auto stageB = [&](int buf, int t, int h) {
    const unsigned short* p = gb + (size_t)t * BK;
    unsigned short* l = &lds[32768 + buf * 16384 + tid * 8];
#pragma unroll
    for (int jj = 0; jj < 2; jj++)
      gload16(p + (size_t)(2 * h + jj) * 64 * KK, l + (2 * h + jj) * 4096);
  };

  auto readB0 = [&](const unsigned short* sb_) {   // 4 reads
#pragma unroll
    for (int n = 0; n < 2; n++) {
      b0[n][0] = *(const s16x8*)(sb_ + brow + n * 16 * BK + ok0);
      b0[n][1] = *(const s16x8*)(sb_ + brow + n * 16 * BK + ok1);
    }
  };
  auto readB1 = [&](const unsigned short* sb_) {   // 4 reads
#pragma unroll
    for (int n = 0; n < 2; n++) {
      b1[n][0] = *(const s16x8*)(sb_ + brow + (32 + n * 16) * BK + ok0);
      b1[n][1] = *(const s16x8*)(sb_ + brow + (32 + n * 16) * BK + ok1);
    }
  };
  auto readAF = [&](const unsigned short* sa_) {   // 8 reads
#pragma unroll
    for (int m = 0; m < 4; m++) {
      af[m][0] = *(const s16x8*)(sa_ + arow + m * 16 * BK + ok0);
      af[m][1] = *(const s16x8*)(sa_ + arow + m * 16 * BK + ok1);
    }
  };
  auto readAF2 = [&](const unsigned short* sa_) {  // 8 reads
#pragma unroll
    for (int m = 0; m < 4; m++) {
      af2[m][0] = *(const s16x8*)(sa_ + arow + (64 + m * 16) * BK + ok0);
      af2[m][1] = *(const s16x8*)(sa_ + arow + (64 + m * 16) * BK + ok1);
    }
  };

  // prologue: tile 0 -> buf0; certify; issue lo-half reads of tile 0 (12 out)
  stageA(0, 0, 0); stageA(0, 0, 1);
  stageB(0, 0, 0); stageB(0, 0, 1);
  VMC(0); SB0();
  __builtin_amdgcn_s_barrier(); SB0();
  readAF(&lds[0]); readB0(&lds[32768]); SB0();

  for (int t = 0; t < NT; ++t) {
    const int cur = t & 1;
    const unsigned short* sa   = &lds[cur * 16384];
    const unsigned short* sb   = &lds[32768 + cur * 16384];
    const unsigned short* sa_n = &lds[(cur ^ 1) * 16384];
    const unsigned short* sb_n = &lds[32768 + (cur ^ 1) * 16384];
    const int tn = (t + 1) & (NT - 1);   // wraps on last iter (dead loads/reads)

    // ===== first half =====
    // hi-half reads of THIS tile first (buf cur certified at t-1 mid-barrier;
    // LDS pipe starts immediately). af2 before b1 (LGKM(4) count relies on it)
    readAF2(sa); SB0();
    readB1(sb); SB0();
    // stage tile t+1 into buf^1 (its readers retired during tile t-1)
    stageA(cur ^ 1, tn, 0); stageA(cur ^ 1, tn, 1);
    stageB(cur ^ 1, tn, 0); stageB(cur ^ 1, tn, 1);
    SB0();

    // gate lo reads of t (issued during t-1 second half)
    LGKM(12); SB0();

    // Q00: af x b0
    __builtin_amdgcn_s_setprio(1);
#pragma unroll
    for (int m = 0; m < 4; m++)
#pragma unroll
      for (int n = 0; n < 2; n++) {
        acc[m][n] = MFMA16(af[m][0], b0[n][0], acc[m][n]);
        acc[m][n] = MFMA16(af[m][1], b0[n][1], acc[m][n]);
      }
    __builtin_amdgcn_s_setprio(0);
    SB0();

    // gate af2 (leaves b1's 4 outstanding)
    LGKM(4); SB0();

    // Q10: af2 x b0  (b0 dead after this)
    __builtin_amdgcn_s_setprio(1);
#pragma unroll
    for (int m = 0; m < 4; m++)
#pragma unroll
      for (int n = 0; n < 2; n++) {
        acc[4 + m][n] = MFMA16(af2[m][0], b0[n][0], acc[4 + m][n]);
        acc[4 + m][n] = MFMA16(af2[m][1], b0[n][1], acc[4 + m][n]);
      }
    __builtin_amdgcn_s_setprio(0);
    SB0();

    // certify buf^1 (stage issued in first half; no counted-vmcnt variant is
    // safe here: every gload half-tile feeds some wave's 2nd-half/next-top read)
    VMC(0); SB0();
    __builtin_amdgcn_s_barrier(); SB0();

    // ===== second half =====
    // b0 of tile t+1 into freed b0 regs (drains under Q01)
    readB0(sb_n); SB0();

    // gate b1(t): out = b1(4)+b0n(4); LGKM(4) retires the 4 oldest = b1
    LGKM(4); SB0();

    // Q01: af x b1  (af dead after this)
    __builtin_amdgcn_s_setprio(1);
#pragma unroll
    for (int m = 0; m < 4; m++)
#pragma unroll
      for (int n = 0; n < 2; n++) {
        acc[m][2 + n] = MFMA16(af[m][0], b1[n][0], acc[m][2 + n]);
        acc[m][2 + n] = MFMA16(af[m][1], b1[n][1], acc[m][2 + n]);
      }
    __builtin_amdgcn_s_setprio(0);
    SB0();

    // af of tile t+1 into freed af regs (drains under Q11)
    readAF(sa_n); SB0();

    // Q11: af2 x b1  (af2, b1 dead after this)
    __builtin_amdgcn_s_setprio(1);
#pragma unroll
    for (int m = 0; m < 4; m++)
#pragma unroll
      for (int n = 0; n < 2; n++) {
        acc[4 + m][2 + n] = MFMA16(af2[m][0], b1[n][0], acc[4 + m][2 + n]);
        acc[4 + m][2 + n] = MFMA16(af2[m][1], b1[n][1], acc[4 + m][2 + n]);
      }
    __builtin_amdgcn_s_setprio(0);
    SB0();
  }

  // ---- epilogue: D layout col = lane&15, row = (lane>>4)*4 + reg ----
  const int crow0 = bmi * BM + wm * 128 + lhi * 4;
  const int ccol0 = bni * BN + wn * 64 + llo;
#pragma unroll
  for (int m = 0; m < 8; m++)
#pragma unroll
    for (int n = 0; n < 4; n++) {
      float* cp = C + (size_t)(crow0 + m * 16) * NN + ccol0 + n * 16;
#pragma unroll
      for (int v = 0; v < 4; v++) cp[(size_t)v * NN] = acc[m][n][v];
    }
}

// ---------- fallback: fused fp32 tiled GEMM (workspace too small) ----------

__device__ __forceinline__ float binq_elem(const float g[4], int j) {
  float aj = fabsf(g[j]);
  int rank = 0;
#pragma unroll
  for (int k = 0; k < 4; k++) {
    if (k == j) continue;
    float ak = fabsf(g[k]);
    rank += (ak > aj || (ak == aj && k < j)) ? 1 : 0;
  }
  return (rank < 2 && g[j] > 0.0f) ? 1.0f : 0.0f;
}

__global__ __launch_bounds__(256) void kfallback(const float* __restrict__ x,
                                                 const float* __restrict__ w,
                                                 float* __restrict__ c) {
  __shared__ float sA[16][17];
  __shared__ float sB[16][17];
  int tx = threadIdx.x, ty = threadIdx.y;
  int row = blockIdx.y * 16 + ty;
  int col = blockIdx.x * 16 + tx;
  float acc = 0.0f;
  for (int k0 = 0; k0 < KK; k0 += 16) {
    int k = k0 + tx;
    const float* g = &w[(size_t)row * KK + (k & ~3)];
    float gv[4] = {g[0], g[1], g[2], g[3]};
    sA[ty][tx] = binq_elem(gv, k & 3);
    sB[ty][tx] = x[(size_t)(k0 + ty) * NN + col];
    __syncthreads();
#pragma unroll
    for (int kk = 0; kk < 16; kk++) acc += sA[ty][kk] * sB[kk][tx];
    __syncthreads();
  }
  c[(size_t)row * NN + col] = acc;
}

// ---------- launcher ----------

extern "C" void kernel_launch(void* const* d_in, const int* in_sizes, int n_in,
                              void* d_out, int out_size, void* d_ws, size_t ws_size,
                              hipStream_t stream) {
  const float* x = (const float*)d_in[0];
  const float* w = (const float*)d_in[1];
  float* out = (float*)d_out;

  const size_t need = (size_t)MM * KK * 2 + (size_t)NN * KK * 2;
  if (ws_size < need) {
    dim3 blk(16, 16);
    dim3 grd(NN / 16, MM / 16);
    kfallback<<<grd, blk, 0, stream>>>(x, w, out);
    return;
  }

  unsigned short* wh = (unsigned short*)d_ws;
  unsigned short* xt = wh + (size_t)MM * KK;

  kpre<<<12288, 256, 0, stream>>>(w, x, wh, xt);
  kgemm<<<dim3((MM / BM) * (NN / BN)), 512, 0, stream>>>(wh, xt, out);
}

// Round 17
// 129.177 us; speedup vs baseline: 1.0155x; 1.0155x over previous
//
#include <hip/hip_runtime.h>

#define MM 4096
#define NN 4096
#define KK 4096
#define BM 256
#define BN 256
#define BK 64
#define NT (KK / BK)

typedef short          s16x8 __attribute__((ext_vector_type(8)));
typedef float          f32x4 __attribute__((ext_vector_type(4)));
typedef unsigned short us4   __attribute__((ext_vector_type(4)));
typedef unsigned short us8   __attribute__((ext_vector_type(8)));

#define MFMA16(a, b, c) __builtin_amdgcn_mfma_f32_16x16x32_bf16((a), (b), (c), 0, 0, 0)
#define SB0() __builtin_amdgcn_sched_barrier(0)
#define LGKM(n) asm volatile("s_waitcnt lgkmcnt(" #n ")" ::: "memory")
#define VMC(n)  asm volatile("s_waitcnt vmcnt(" #n ")" ::: "memory")

// ---------- helpers ----------

__device__ __forceinline__ unsigned short f2bf(float f) {
  unsigned int u = __float_as_uint(f);
  u += 0x7fffu + ((u >> 16) & 1u);
  return (unsigned short)(u >> 16);
}

__device__ __forceinline__ void gload16(const void* g, void* l) {
  __builtin_amdgcn_global_load_lds(
      (const __attribute__((address_space(1))) void*)g,
      (__attribute__((address_space(3))) void*)l, 16, 0, 0);
}

// ---------- kernel 1: fused preprocessing ----------
// blocks [0, 8192):  2:4 mask + binarize + cvt -> W_h bf16 (M x K)
// blocks [8192, 12288): x (K x N f32) -> xT (N x K bf16), 64x64 LDS transpose

__global__ __launch_bounds__(256) void kpre(const float* __restrict__ w,
                                            const float* __restrict__ x,
                                            unsigned short* __restrict__ wh,
                                            unsigned short* __restrict__ xt) {
  __shared__ float tile[64][65];
  const int t = threadIdx.x;

  if (blockIdx.x < 8192) {
    // ---- quant path ----
    int idx = blockIdx.x * 256 + t;
    const float4* p = (const float4*)w;
    float4 g0 = p[(size_t)idx * 2];
    float4 g1 = p[(size_t)idx * 2 + 1];
    float v[8] = {g0.x, g0.y, g0.z, g0.w, g1.x, g1.y, g1.z, g1.w};
    us8 o;
#pragma unroll
    for (int g = 0; g < 2; g++) {
      float av[4];
#pragma unroll
      for (int j = 0; j < 4; j++) av[j] = fabsf(v[g * 4 + j]);
#pragma unroll
      for (int j = 0; j < 4; j++) {
        int rank = 0;
#pragma unroll
        for (int k = 0; k < 4; k++) {
          if (k == j) continue;
          rank += (av[k] > av[j] || (av[k] == av[j] && k < j)) ? 1 : 0;
        }
        o[g * 4 + j] = (rank < 2 && v[g * 4 + j] > 0.0f) ? (unsigned short)0x3F80
                                                         : (unsigned short)0;
      }
    }
    *(us8*)(wh + (size_t)idx * 8) = o;
    return;
  }

  // ---- transpose path ----
  int bid2 = blockIdx.x - 8192;
  int bn = bid2 & 63;
  int bk = bid2 >> 6;
  int tc = (t & 15) << 2;
  int tr = t >> 4;
  const float* src = x + (size_t)(bk * 64 + tr) * NN + bn * 64 + tc;
#pragma unroll
  for (int i = 0; i < 4; i++) {
    float4 v = *(const float4*)(src + (size_t)i * 16 * NN);
    int r = tr + i * 16;
    tile[r][tc + 0] = v.x; tile[r][tc + 1] = v.y;
    tile[r][tc + 2] = v.z; tile[r][tc + 3] = v.w;
  }
  __syncthreads();
  unsigned short* dst = xt + (size_t)(bn * 64 + tr) * KK + bk * 64 + tc;
#pragma unroll
  for (int i = 0; i < 4; i++) {
    int n = tr + i * 16;
    us4 o;
    o.x = f2bf(tile[tc + 0][n]);
    o.y = f2bf(tile[tc + 1][n]);
    o.z = f2bf(tile[tc + 2][n]);
    o.w = f2bf(tile[tc + 3][n]);
    *(us4*)(dst + (size_t)i * 16 * KK) = o;
  }
}

// ---------- kernel 2: 256x256 GEMM, balanced 12/12 read split -------------
// Session champion (round 15, 128.9 us total / kgemm 104.4 us, 1310 TF,
// MfmaUtil 56%, 0 bank conflicts). Each half-tile carries 12 ds_reads under
// 32 MFMA; stage block at tile top (order vs reads matters: stage first).
// Per-wave ledger (in-order DS retire):
//   top: out=12 {lo of t}; +12 {af2;b1 of t} -> out=24
//   LGKM(12) => lo ready -> Q00 ; LGKM(4) => af2 ready -> Q10
//   VMC(0)+barrier (buf^1 certified)
//   +4 {b0 of t+1} ; LGKM(4) => b1 ready -> Q01
//   +8 {af of t+1} ; Q11 ; loop (invariant restored)

__global__ __launch_bounds__(512, 2) void kgemm(const unsigned short* __restrict__ A,
                                                const unsigned short* __restrict__ B,
                                                float* __restrict__ C) {
  __shared__ __align__(16) unsigned short lds[4 * BM * BK];  // A0|A1|B0|B1, 128 KiB

  const int tid  = threadIdx.x;
  // XCD swizzle: xcd = bid&7; each XCD owns a 4x8 rectangle of the 16x16 grid.
  const int bid  = blockIdx.x;
  const int xcd  = bid & 7;
  const int j    = bid >> 3;
  const int bmi  = (xcd >> 1) * 4 + (j >> 3);
  const int bni  = (xcd & 1) * 8 + (j & 7);
  const int lane = tid & 63;
  const int wave = tid >> 6;
  const int wm   = wave >> 2;
  const int wn   = wave & 3;
  const int llo  = lane & 15;
  const int lhi  = lane >> 4;

  // staging addresses (linear LDS dest; inverse-swizzled global source)
  const int srow  = tid >> 3;
  const int scol  = (tid & 7) << 3;
  const int scolz = scol ^ ((srow & 7) << 3);
  const unsigned short* ga = A + (size_t)(bmi * BM + srow) * KK + scolz;
  const unsigned short* gb = B + (size_t)(bni * BN + srow) * KK + scolz;

  // fragment read offsets (swizzled) — proven 0-conflict pattern
  const int swz  = (llo & 7) << 3;
  const int ok0  = (lhi * 8) ^ swz;
  const int ok1  = (32 + lhi * 8) ^ swz;
  const int arow = (wm * 128 + llo) * BK;
  const int brow = (wn * 64 + llo) * BK;

  f32x4 acc[8][4] = {};
  s16x8 af[4][2], af2[4][2], b0[2][2], b1[2][2];

  auto stageA = [&](int buf, int t, int h) {
    const unsigned short* p = ga + (size_t)t * BK;
    unsigned short* l = &lds[buf * 16384 + tid * 8];
#pragma unroll
    for (int jj = 0; jj < 2; jj++)
      gload16(p + (size_t)(2 * h + jj) * 64 * KK, l + (2 * h + jj) * 4096);
  };
  auto stageB = [&](int buf, int t, int h) {
    const unsigned short* p = gb + (size_t)t * BK;
    unsigned short* l = &lds[32768 + buf * 16384 + tid * 8];
#pragma unroll
    for (int jj = 0; jj < 2; jj++)
      gload16(p + (size_t)(2 * h + jj) * 64 * KK, l + (2 * h + jj) * 4096);
  };

  auto readB0 = [&](const unsigned short* sb_) {   // 4 reads
#pragma unroll
    for (int n = 0; n < 2; n++) {
      b0[n][0] = *(const s16x8*)(sb_ + brow + n * 16 * BK + ok0);
      b0[n][1] = *(const s16x8*)(sb_ + brow + n * 16 * BK + ok1);
    }
  };
  auto readB1 = [&](const unsigned short* sb_) {   // 4 reads
#pragma unroll
    for (int n = 0; n < 2; n++) {
      b1[n][0] = *(const s16x8*)(sb_ + brow + (32 + n * 16) * BK + ok0);
      b1[n][1] = *(const s16x8*)(sb_ + brow + (32 + n * 16) * BK + ok1);
    }
  };
  auto readAF = [&](const unsigned short* sa_) {   // 8 reads
#pragma unroll
    for (int m = 0; m < 4; m++) {
      af[m][0] = *(const s16x8*)(sa_ + arow + m * 16 * BK + ok0);
      af[m][1] = *(const s16x8*)(sa_ + arow + m * 16 * BK + ok1);
    }
  };
  auto readAF2 = [&](const unsigned short* sa_) {  // 8 reads
#pragma unroll
    for (int m = 0; m < 4; m++) {
      af2[m][0] = *(const s16x8*)(sa_ + arow + (64 + m * 16) * BK + ok0);
      af2[m][1] = *(const s16x8*)(sa_ + arow + (64 + m * 16) * BK + ok1);
    }
  };

  // prologue: tile 0 -> buf0; certify; issue lo-half reads of tile 0 (12 out)
  stageA(0, 0, 0); stageA(0, 0, 1);
  stageB(0, 0, 0); stageB(0, 0, 1);
  VMC(0); SB0();
  __builtin_amdgcn_s_barrier(); SB0();
  readAF(&lds[0]); readB0(&lds[32768]); SB0();

  for (int t = 0; t < NT; ++t) {
    const int cur = t & 1;
    const unsigned short* sa   = &lds[cur * 16384];
    const unsigned short* sb   = &lds[32768 + cur * 16384];
    const unsigned short* sa_n = &lds[(cur ^ 1) * 16384];
    const unsigned short* sb_n = &lds[32768 + (cur ^ 1) * 16384];
    const int tn = (t + 1) & (NT - 1);   // wraps on last iter (dead loads/reads)

    // ===== first half =====
    // stage tile t+1 into buf^1 (its readers retired during tile t-1)
    stageA(cur ^ 1, tn, 0); stageA(cur ^ 1, tn, 1);
    stageB(cur ^ 1, tn, 0); stageB(cur ^ 1, tn, 1);
    SB0();
    // hi-half reads of THIS tile (buf cur certified at t-1 mid-barrier);
    // af2 before b1 (LGKM(4) count relies on it)
    readAF2(sa); SB0();
    readB1(sb); SB0();

    // gate lo reads of t (issued during t-1 second half)
    LGKM(12); SB0();

    // Q00: af x b0
    __builtin_amdgcn_s_setprio(1);
#pragma unroll
    for (int m = 0; m < 4; m++)
#pragma unroll
      for (int n = 0; n < 2; n++) {
        acc[m][n] = MFMA16(af[m][0], b0[n][0], acc[m][n]);
        acc[m][n] = MFMA16(af[m][1], b0[n][1], acc[m][n]);
      }
    __builtin_amdgcn_s_setprio(0);
    SB0();

    // gate af2 (leaves b1's 4 outstanding)
    LGKM(4); SB0();

    // Q10: af2 x b0  (b0 dead after this)
    __builtin_amdgcn_s_setprio(1);
#pragma unroll
    for (int m = 0; m < 4; m++)
#pragma unroll
      for (int n = 0; n < 2; n++) {
        acc[4 + m][n] = MFMA16(af2[m][0], b0[n][0], acc[4 + m][n]);
        acc[4 + m][n] = MFMA16(af2[m][1], b0[n][1], acc[4 + m][n]);
      }
    __builtin_amdgcn_s_setprio(0);
    SB0();

    // certify buf^1 (stage issued at tile top: full first half of cover).
    // No counted-vmcnt variant is safe here: every gload half-tile feeds
    // some wave's second-half or next-top read.
    VMC(0); SB0();
    __builtin_amdgcn_s_barrier(); SB0();

    // ===== second half =====
    // b0 of tile t+1 into freed b0 regs (drains under Q01)
    readB0(sb_n); SB0();

    // gate b1(t): out = b1(4)+b0n(4); LGKM(4) retires the 4 oldest = b1
    LGKM(4); SB0();

    // Q01: af x b1  (af dead after this)
    __builtin_amdgcn_s_setprio(1);
#pragma unroll
    for (int m = 0; m < 4; m++)
#pragma unroll
      for (int n = 0; n < 2; n++) {
        acc[m][2 + n] = MFMA16(af[m][0], b1[n][0], acc[m][2 + n]);
        acc[m][2 + n] = MFMA16(af[m][1], b1[n][1], acc[m][2 + n]);
      }
    __builtin_amdgcn_s_setprio(0);
    SB0();

    // af of tile t+1 into freed af regs (drains under Q11)
    readAF(sa_n); SB0();

    // Q11: af2 x b1  (af2, b1 dead after this)
    __builtin_amdgcn_s_setprio(1);
#pragma unroll
    for (int m = 0; m < 4; m++)
#pragma unroll
      for (int n = 0; n < 2; n++) {
        acc[4 + m][2 + n] = MFMA16(af2[m][0], b1[n][0], acc[4 + m][2 + n]);
        acc[4 + m][2 + n] = MFMA16(af2[m][1], b1[n][1], acc[4 + m][2 + n]);
      }
    __builtin_amdgcn_s_setprio(0);
    SB0();
  }

  // ---- epilogue: D layout col = lane&15, row = (lane>>4)*4 + reg ----
  const int crow0 = bmi * BM + wm * 128 + lhi * 4;
  const int ccol0 = bni * BN + wn * 64 + llo;
#pragma unroll
  for (int m = 0; m < 8; m++)
#pragma unroll
    for (int n = 0; n < 4; n++) {
      float* cp = C + (size_t)(crow0 + m * 16) * NN + ccol0 + n * 16;
#pragma unroll
      for (int v = 0; v < 4; v++) cp[(size_t)v * NN] = acc[m][n][v];
    }
}

// ---------- fallback: fused fp32 tiled GEMM (workspace too small) ----------

__device__ __forceinline__ float binq_elem(const float g[4], int j) {
  float aj = fabsf(g[j]);
  int rank = 0;
#pragma unroll
  for (int k = 0; k < 4; k++) {
    if (k == j) continue;
    float ak = fabsf(g[k]);
    rank += (ak > aj || (ak == aj && k < j)) ? 1 : 0;
  }
  return (rank < 2 && g[j] > 0.0f) ? 1.0f : 0.0f;
}

__global__ __launch_bounds__(256) void kfallback(const float* __restrict__ x,
                                                 const float* __restrict__ w,
                                                 float* __restrict__ c) {
  __shared__ float sA[16][17];
  __shared__ float sB[16][17];
  int tx = threadIdx.x, ty = threadIdx.y;
  int row = blockIdx.y * 16 + ty;
  int col = blockIdx.x * 16 + tx;
  float acc = 0.0f;
  for (int k0 = 0; k0 < KK; k0 += 16) {
    int k = k0 + tx;
    const float* g = &w[(size_t)row * KK + (k & ~3)];
    float gv[4] = {g[0], g[1], g[2], g[3]};
    sA[ty][tx] = binq_elem(gv, k & 3);
    sB[ty][tx] = x[(size_t)(k0 + ty) * NN + col];
    __syncthreads();
#pragma unroll
    for (int kk = 0; kk < 16; kk++) acc += sA[ty][kk] * sB[kk][tx];
    __syncthreads();
  }
  c[(size_t)row * NN + col] = acc;
}

// ---------- launcher ----------

extern "C" void kernel_launch(void* const* d_in, const int* in_sizes, int n_in,
                              void* d_out, int out_size, void* d_ws, size_t ws_size,
                              hipStream_t stream) {
  const float* x = (const float*)d_in[0];
  const float* w = (const float*)d_in[1];
  float* out = (float*)d_out;

  const size_t need = (size_t)MM * KK * 2 + (size_t)NN * KK * 2;
  if (ws_size < need) {
    dim3 blk(16, 16);
    dim3 grd(NN / 16, MM / 16);
    kfallback<<<grd, blk, 0, stream>>>(x, w, out);
    return;
  }

  unsigned short* wh = (unsigned short*)d_ws;
  unsigned short* xt = wh + (size_t)MM * KK;

  kpre<<<12288, 256, 0, stream>>>(w, x, wh, xt);
  kgemm<<<dim3((MM / BM) * (NN / BN)), 512, 0, stream>>>(wh, xt, out);
}

// Round 18
// 95.669 us; speedup vs baseline: 1.3712x; 1.3503x over previous
//
#include <hip/hip_runtime.h>

#define MM 4096
#define NN 4096
#define KK 4096
#define BM 256
#define BN 256
#define BK 64
#define NT (KK / BK)
#define QSCALE 24.0f

typedef int           i32x4 __attribute__((ext_vector_type(4)));
typedef unsigned char uc8   __attribute__((ext_vector_type(8)));

#define MFMAI8(a, b, c) __builtin_amdgcn_mfma_i32_16x16x64_i8((a), (b), (c), 0, 0, 0)
#define SB0() __builtin_amdgcn_sched_barrier(0)
#define LGKM(n) asm volatile("s_waitcnt lgkmcnt(" #n ")" ::: "memory")
#define VMC(n)  asm volatile("s_waitcnt vmcnt(" #n ")" ::: "memory")

// ---------- helpers ----------

__device__ __forceinline__ void gload16(const void* g, void* l) {
  __builtin_amdgcn_global_load_lds(
      (const __attribute__((address_space(1))) void*)g,
      (__attribute__((address_space(3))) void*)l, 16, 0, 0);
}

__device__ __forceinline__ int q8(float v) {
  int q = (int)rintf(v * QSCALE);
  q = q > 127 ? 127 : q;
  q = q < -127 ? -127 : q;
  return q & 255;
}

// ---------- kernel 1: fused preprocessing (i8 outputs) ----------
// blocks [0, 8192):  2:4 mask + binarize -> wh i8 {0,1} (M x K)
// blocks [8192, 12288): x (K x N f32) -> xT i8 (N x K), 64x64 LDS transpose,
//   xq = clamp(rint(24*x), -127, 127)  (dequant scale 1/24 in GEMM epilogue)

__global__ __launch_bounds__(256) void kpre(const float* __restrict__ w,
                                            const float* __restrict__ x,
                                            signed char* __restrict__ wh,
                                            signed char* __restrict__ xt) {
  __shared__ float tile[64][65];
  const int t = threadIdx.x;

  if (blockIdx.x < 8192) {
    // ---- quant path ----
    int idx = blockIdx.x * 256 + t;
    const float4* p = (const float4*)w;
    float4 g0 = p[(size_t)idx * 2];
    float4 g1 = p[(size_t)idx * 2 + 1];
    float v[8] = {g0.x, g0.y, g0.z, g0.w, g1.x, g1.y, g1.z, g1.w};
    uc8 o;
#pragma unroll
    for (int g = 0; g < 2; g++) {
      float av[4];
#pragma unroll
      for (int j = 0; j < 4; j++) av[j] = fabsf(v[g * 4 + j]);
#pragma unroll
      for (int j = 0; j < 4; j++) {
        int rank = 0;
#pragma unroll
        for (int k = 0; k < 4; k++) {
          if (k == j) continue;
          rank += (av[k] > av[j] || (av[k] == av[j] && k < j)) ? 1 : 0;
        }
        o[g * 4 + j] = (rank < 2 && v[g * 4 + j] > 0.0f) ? (unsigned char)1
                                                         : (unsigned char)0;
      }
    }
    *(uc8*)(wh + (size_t)idx * 8) = o;
    return;
  }

  // ---- transpose + quantize path ----
  int bid2 = blockIdx.x - 8192;
  int bn = bid2 & 63;
  int bk = bid2 >> 6;
  int tc = (t & 15) << 2;
  int tr = t >> 4;
  const float* src = x + (size_t)(bk * 64 + tr) * NN + bn * 64 + tc;
#pragma unroll
  for (int i = 0; i < 4; i++) {
    float4 v = *(const float4*)(src + (size_t)i * 16 * NN);
    int r = tr + i * 16;
    tile[r][tc + 0] = v.x; tile[r][tc + 1] = v.y;
    tile[r][tc + 2] = v.z; tile[r][tc + 3] = v.w;
  }
  __syncthreads();
#pragma unroll
  for (int i = 0; i < 4; i++) {
    int n = tr + i * 16;
    unsigned int q = (unsigned)q8(tile[tc + 0][n])
                   | ((unsigned)q8(tile[tc + 1][n]) << 8)
                   | ((unsigned)q8(tile[tc + 2][n]) << 16)
                   | ((unsigned)q8(tile[tc + 3][n]) << 24);
    *(unsigned int*)(xt + (size_t)(bn * 64 + n) * KK + bk * 64 + tc) = q;
  }
}

// ---------- kernel 2: 256x256 i8 GEMM, mfma_i32_16x16x64_i8 ---------------
// 8 waves (2M x 4N), BK=64 = ONE mfma K-step. Per wave per tile: 12 ds_reads
// (8 A + 4 B frags, 16B each = exactly one mfma operand) + 32 MFMA. LDS 64KB
// (A dbuf 2x16K | B dbuf 2x16K). 64B rows: swizzle pg=((r&1)*4+g)^((r>>1)&7)
// (<=2-way = free); staged via inverse-swizzled global source (rule 21).
// Balanced ledger (in-order DS retire):
//   top: out=8 {af-lo,bf of t}; stage(t+1) 4 gloads; +4 af-hi -> out=12
//   LGKM(4) => af-lo+bf ready -> Q-lo (16 MFMA)
//   VMC(0)+barrier (buf^1 certified)
//   +4 af-lo(t+1) ; LGKM(4) => af-hi ready -> Q-hi (16 MFMA)
//   +4 bf(t+1) ; loop (invariant restored)
// Epilogue: C = (float)acc * (1/24)  [C/D layout dtype-independent, m121/m127]

__global__ __launch_bounds__(512, 2) void kgemm(const signed char* __restrict__ A,
                                                const signed char* __restrict__ B,
                                                float* __restrict__ C) {
  __shared__ __align__(16) char lds[65536];  // A0|A1 @0, B0|B1 @32768

  const int tid  = threadIdx.x;
  // XCD swizzle: xcd = bid&7; each XCD owns a 4x8 rectangle of the 16x16 grid.
  const int bid  = blockIdx.x;
  const int xcd  = bid & 7;
  const int j    = bid >> 3;
  const int bmi  = (xcd >> 1) * 4 + (j >> 3);
  const int bni  = (xcd & 1) * 8 + (j & 7);
  const int lane = tid & 63;
  const int wave = tid >> 6;
  const int wm   = wave >> 2;
  const int wn   = wave & 3;
  const int llo  = lane & 15;
  const int lhi  = lane >> 4;

  // staging source (inverse-swizzled): thread t writes linear LDS granule t;
  // line L = t>>3, phys pos pgs = t&7; logical lg = pgs ^ (L&7);
  // row-in-chunk rl = 2L | lg>>2, k-quarter gq = lg&3.
  const int L   = tid >> 3;
  const int pgs = tid & 7;
  const int lg  = pgs ^ (L & 7);
  const int rl  = (L << 1) | (lg >> 2);
  const int gq  = lg & 3;
  const signed char* ga = A + (size_t)(bmi * BM + rl) * KK + gq * 16;
  const signed char* gb = B + (size_t)(bni * BN + rl) * KK + gq * 16;

  // fragment read offsets: logical (row r, k-quarter lhi) at
  // chunk(r>>7)*8192 + (r&127 >>1)*128 + (((r&1)*4+lhi)^((r>>1)&7))*16
  const int pg   = (((llo & 1) << 2) + lhi) ^ ((llo >> 1) & 7);
  const int aoff = wm * 8192 + (llo >> 1) * 128 + pg * 16;            // + m*1024
  const int boff = (wn >> 1) * 8192 + ((wn & 1) * 32 + (llo >> 1)) * 128 + pg * 16;  // + n*1024

  i32x4 acc[8][4] = {};
  i32x4 afl[4], afh[4], bf[4];

  auto stage = [&](int buf, int t) {   // 2 A-gloads + 2 B-gloads
#pragma unroll
    for (int c = 0; c < 2; c++)
      gload16(ga + (size_t)c * 128 * KK + t * 64,
              lds + buf * 16384 + c * 8192 + tid * 16);
#pragma unroll
    for (int c = 0; c < 2; c++)
      gload16(gb + (size_t)c * 128 * KK + t * 64,
              lds + 32768 + buf * 16384 + c * 8192 + tid * 16);
  };
  auto readAFlo = [&](int buf) {
#pragma unroll
    for (int m = 0; m < 4; m++)
      afl[m] = *(const i32x4*)(lds + buf * 16384 + aoff + m * 1024);
  };
  auto readAFhi = [&](int buf) {
#pragma unroll
    for (int m = 0; m < 4; m++)
      afh[m] = *(const i32x4*)(lds + buf * 16384 + aoff + (4 + m) * 1024);
  };
  auto readBF = [&](int buf) {
#pragma unroll
    for (int n = 0; n < 4; n++)
      bf[n] = *(const i32x4*)(lds + 32768 + buf * 16384 + boff + n * 1024);
  };

  // prologue: tile 0 -> buf0; certify; issue lo reads (out=8)
  stage(0, 0);
  VMC(0); SB0();
  __builtin_amdgcn_s_barrier(); SB0();
  readAFlo(0); readBF(0); SB0();

  for (int t = 0; t < NT; ++t) {
    const int cur = t & 1;
    const int nb  = cur ^ 1;
    const int tn  = (t + 1) & (NT - 1);  // wraps on last iter (dead loads/reads)

    // stage tile t+1 into buf^1 (its readers retired during tile t-1)
    stage(nb, tn); SB0();
    // af-hi of THIS tile (out -> 12)
    readAFhi(cur); SB0();

    // gate af-lo + bf (8 oldest of 12)
    LGKM(4); SB0();

    // Q-lo: af-lo x bf -> acc[0..3][*]
    __builtin_amdgcn_s_setprio(1);
#pragma unroll
    for (int m = 0; m < 4; m++)
#pragma unroll
      for (int n = 0; n < 4; n++)
        acc[m][n] = MFMAI8(afl[m], bf[n], acc[m][n]);
    __builtin_amdgcn_s_setprio(0);
    SB0();

    // certify buf^1
    VMC(0); SB0();
    __builtin_amdgcn_s_barrier(); SB0();

    // af-lo of t+1 into freed regs (out: af-hi 4 + af-lo_n 4)
    readAFlo(nb); SB0();

    // gate af-hi (4 oldest)
    LGKM(4); SB0();

    // Q-hi: af-hi x bf -> acc[4..7][*]  (bf dead after this)
    __builtin_amdgcn_s_setprio(1);
#pragma unroll
    for (int m = 0; m < 4; m++)
#pragma unroll
      for (int n = 0; n < 4; n++)
        acc[4 + m][n] = MFMAI8(afh[m], bf[n], acc[4 + m][n]);
    __builtin_amdgcn_s_setprio(0);
    SB0();

    // bf of t+1 (out -> 8; invariant restored)
    readBF(nb); SB0();
  }

  // ---- epilogue: D layout col = lane&15, row = (lane>>4)*4 + reg; scale 1/24
  const int crow0 = bmi * BM + wm * 128 + lhi * 4;
  const int ccol0 = bni * BN + wn * 64 + llo;
  const float ds = 1.0f / QSCALE;
#pragma unroll
  for (int m = 0; m < 8; m++)
#pragma unroll
    for (int n = 0; n < 4; n++) {
      float* cp = C + (size_t)(crow0 + m * 16) * NN + ccol0 + n * 16;
#pragma unroll
      for (int v = 0; v < 4; v++) cp[(size_t)v * NN] = (float)acc[m][n][v] * ds;
    }
}

// ---------- fallback: fused fp32 tiled GEMM (workspace too small) ----------

__device__ __forceinline__ float binq_elem(const float g[4], int j) {
  float aj = fabsf(g[j]);
  int rank = 0;
#pragma unroll
  for (int k = 0; k < 4; k++) {
    if (k == j) continue;
    float ak = fabsf(g[k]);
    rank += (ak > aj || (ak == aj && k < j)) ? 1 : 0;
  }
  return (rank < 2 && g[j] > 0.0f) ? 1.0f : 0.0f;
}

__global__ __launch_bounds__(256) void kfallback(const float* __restrict__ x,
                                                 const float* __restrict__ w,
                                                 float* __restrict__ c) {
  __shared__ float sA[16][17];
  __shared__ float sB[16][17];
  int tx = threadIdx.x, ty = threadIdx.y;
  int row = blockIdx.y * 16 + ty;
  int col = blockIdx.x * 16 + tx;
  float acc = 0.0f;
  for (int k0 = 0; k0 < KK; k0 += 16) {
    int k = k0 + tx;
    const float* g = &w[(size_t)row * KK + (k & ~3)];
    float gv[4] = {g[0], g[1], g[2], g[3]};
    sA[ty][tx] = binq_elem(gv, k & 3);
    sB[ty][tx] = x[(size_t)(k0 + ty) * NN + col];
    __syncthreads();
#pragma unroll
    for (int kk = 0; kk < 16; kk++) acc += sA[ty][kk] * sB[kk][tx];
    __syncthreads();
  }
  c[(size_t)row * NN + col] = acc;
}

// ---------- launcher ----------

extern "C" void kernel_launch(void* const* d_in, const int* in_sizes, int n_in,
                              void* d_out, int out_size, void* d_ws, size_t ws_size,
                              hipStream_t stream) {
  const float* x = (const float*)d_in[0];
  const float* w = (const float*)d_in[1];
  float* out = (float*)d_out;

  const size_t need = (size_t)MM * KK + (size_t)NN * KK;  // 33.6 MB (i8)
  if (ws_size < need) {
    dim3 blk(16, 16);
    dim3 grd(NN / 16, MM / 16);
    kfallback<<<grd, blk, 0, stream>>>(x, w, out);
    return;
  }

  signed char* wh = (signed char*)d_ws;
  signed char* xt = wh + (size_t)MM * KK;

  kpre<<<12288, 256, 0, stream>>>(w, x, wh, xt);
  kgemm<<<dim3((MM / BM) * (NN / BN)), 512, 0, stream>>>(wh, xt, out);
}